// Round 12
// baseline (231.832 us; speedup 1.0000x reference)
//
#include <hip/hip_runtime.h>
#include <hip/hip_bf16.h>
#include <math.h>

#define C_DIM 1024
#define QKS  2048    // Q|K row stride in bf16 workspace

typedef __attribute__((ext_vector_type(8))) short bf16x8;   // 8 bf16 = 4 VGPRs
typedef __attribute__((ext_vector_type(4))) float f32x4;    // MFMA C/D

__device__ __forceinline__ unsigned short f2bf(float f) {
  __hip_bfloat16 h = __float2bfloat16(f);
  return *(reinterpret_cast<unsigned short*>(&h));
}
__device__ __forceinline__ float bf2f(unsigned short u) {
  return __uint_as_float(((unsigned int)u) << 16);
}
__device__ __forceinline__ f32x4 mfma16(bf16x8 a, bf16x8 b, f32x4 c) {
  return __builtin_amdgcn_mfma_f32_16x16x32_bf16(a, b, c, 0, 0, 0);
}
__device__ __forceinline__ void gload_lds16(const unsigned short* g,
                                            unsigned short* l) {
  __builtin_amdgcn_global_load_lds(
      (const __attribute__((address_space(1))) void*)(g),
      (__attribute__((address_space(3))) void*)(l), 16, 0, 0);
}

#define VMCNT(n)  asm volatile("s_waitcnt vmcnt(" #n ")" ::: "memory")
#define LGKMCNT0  asm volatile("s_waitcnt lgkmcnt(0)" ::: "memory")
#define SBAR      __builtin_amdgcn_sched_barrier(0)
#define BARRIER   __builtin_amdgcn_s_barrier()

// ---------------------------------------------------------------------------
// prep: merged {cast x fp32 -> xb bf16} + {W [1024][3072] fp32 -> WT
// [3072][1024] bf16 transpose}. Blocks [0,nc): cast; blocks [nc,nc+768):
// one 64x64 transpose tile each.
// ---------------------------------------------------------------------------
__global__ __launch_bounds__(256) void prep(
    const float* __restrict__ x, const float* __restrict__ W,
    unsigned short* __restrict__ xb, unsigned short* __restrict__ WT, int nc) {
  __shared__ float Ls[64][65];
  const int id = (int)blockIdx.x;
  if (id < nc) {
    const int i = (id * 256 + threadIdx.x) << 2;
    float4 v = *(const float4*)(x + i);
    ushort4 u;
    u.x = f2bf(v.x); u.y = f2bf(v.y); u.z = f2bf(v.z); u.w = f2bf(v.w);
    *(ushort4*)(xb + i) = u;
    return;
  }
  const int id2 = id - nc;
  const int n0 = (id2 % 48) * 64;
  const int k0 = (id2 / 48) * 64;
  const int c = (threadIdx.x & 15) << 2;
  const int r = threadIdx.x >> 4;
#pragma unroll
  for (int rr = 0; rr < 64; rr += 16) {
    float4 v = *(const float4*)(W + (size_t)(k0 + r + rr) * 3072 + n0 + c);
    Ls[r + rr][c + 0] = v.x; Ls[r + rr][c + 1] = v.y;
    Ls[r + rr][c + 2] = v.z; Ls[r + rr][c + 3] = v.w;
  }
  __syncthreads();
#pragma unroll
  for (int rr = 0; rr < 64; rr += 16) {
    const int X = r + rr;
    ushort4 u;
    u.x = f2bf(Ls[c + 0][X]); u.y = f2bf(Ls[c + 1][X]);
    u.z = f2bf(Ls[c + 2][X]); u.w = f2bf(Ls[c + 3][X]);
    *(ushort4*)(WT + (size_t)(n0 + X) * C_DIM + k0 + c) = u;
  }
}

// ---------------------------------------------------------------------------
// gemm256<MODE>: 256x256-tile, BK=64, 512-thread (8-wave, 2Mx4N) 8-phase
// GEMM with counted vmcnt (T3+T4), LDS XOR-swizzle (T2), setprio (T5).
// (Engine unchanged from R4/R10 -- verified at NT in {4,8,12,16}; odd-NT tail
// re-traced: t=NT-2 takes VMCNT(4), t=NT-1 VMCNT(0) -- ledger closes.)
// MODE 4: merged QKV (QK: bf16+bias[col]; V^T: bf16+bias[row]).
//         Blocks beyond nQK+nV: zero-fill out rows [512,T) on QKV's idle
//         CUs (pre-zeroes PV's atomic target region; stream-ordered).
// MODE 2: S = Q K^T * 1/32, lower-triangle 256-tiles, bf16
// MODE 3: O = P V, BALANCED split-K: tile (bi,nx) gets n=ceil(4(bi+1)/10)
//         chunks (max chunk 10 K-units=640) -> 244 blocks <= 256 CUs, one
//         round, critical path 10 units vs 16. Multi-chunk tiles atomic
//         (rows >= 512 pre-zeroed); bi=0,1 single-chunk non-atomic.
// ---------------------------------------------------------------------------
template <int MODE>
__global__ __launch_bounds__(512) void gemm256(
    const unsigned short* __restrict__ A_, const unsigned short* __restrict__ BT_,
    void* __restrict__ Cv, const float* __restrict__ bias_,
    int lda, int ldb, int ldc, int T, float* __restrict__ zout) {
  __shared__ __align__(16) unsigned short As[2][2][128][64];  // 64 KB
  __shared__ __align__(16) unsigned short Bs[2][2][128][64];  // 64 KB

  const int tid = threadIdx.x, lane = tid & 63, w = tid >> 6;
  const int wr = w >> 2, wc = w & 3;          // wave grid 2M x 4N
  const int qd = lane >> 4, n16 = lane & 15;

  const unsigned short* A  = A_;
  const unsigned short* BT = BT_;
  const float* bias = bias_;
  unsigned short* Cb = (unsigned short*)Cv;
  float* Cf = (float*)Cv;
  int ldc_ = ldc;
  int m0, n0, kbeg = 0, kend = C_DIM;
  bool use_atomic = false, rowbias = false;

  if (MODE == 4) {
    const int nQKx = QKS >> 8;
    const int nQK  = (T >> 8) * nQKx;
    const int nV   = (C_DIM >> 8) * (T >> 8);
    int id = (int)blockIdx.x;
    if (id >= nQK + nV) {                // zero-fill blocks (idle-CU work)
      const int zb = id - (nQK + nV);
      const int ZB = (int)gridDim.x - (nQK + nV);
      const int n4 = ((T - 512) * C_DIM) >> 2;
      const float4 z = {0.f, 0.f, 0.f, 0.f};
      for (int i = zb * 512 + tid; i < n4; i += ZB * 512)
        *(float4*)(zout + (size_t)512 * C_DIM + ((size_t)i << 2)) = z;
      return;
    }
    if (id < nQK) {                      // Q|K part: xb @ WT^T
      m0 = (id / nQKx) << 8; n0 = (id % nQKx) << 8;
    } else {                             // V^T part: Wv^T @ xb^T
      id -= nQK;
      const int nVx = T >> 8;
      m0 = (id / nVx) << 8; n0 = (id % nVx) << 8;
      A  = BT_ + (size_t)QKS * C_DIM;
      BT = A_;
      Cb = (unsigned short*)Cv + (size_t)T * QKS;   // vtb
      bias = bias_ + QKS; rowbias = true; ldc_ = T;
    }
  } else if (MODE == 2) {
    if ((int)blockIdx.x > (int)blockIdx.y) return;  // upper triangle: skip
    m0 = (int)blockIdx.y << 8; n0 = (int)blockIdx.x << 8;
  } else {  // MODE 3: balanced split-K PV
    int id = (int)blockIdx.x;
    int bi = 0, nloc = 1, units = 4;
    for (;; ++bi) {
      units = (bi + 1) << 2;             // K-tiles (of 64) for row-tile bi
      nloc  = (units + 9) / 10;          // chunks: max 10 units each
      const int span = nloc << 2;        // x4 col-tiles
      if (id < span) break;
      id -= span;
    }
    const int nx = id & 3, ch = id >> 2;
    const int base = units / nloc, rem = units % nloc;
    const int u0 = ch * base + (ch < rem ? ch : rem);
    const int u1 = u0 + base + (ch < rem ? 1 : 0);
    m0 = bi << 8; n0 = nx << 8;
    kbeg = u0 << 6; kend = u1 << 6;
    use_atomic = (nloc > 1);             // rows >= 512 pre-zeroed (bi >= 2)
  }

  const int NT = (kend - kbeg) >> 6;    // K-tiles of 64 (>=1; may be odd)

  // ---- staging source pointers (pre-swizzled global k-unit, rule #21)
  const int l3 = lane >> 3;                       // = (phys LDS row)&7
  const int su = (((lane & 7) ^ l3) << 3);        // swizzled k elem offset
  const unsigned short* asrc[2][2];
  const unsigned short* bsrc[2][2];
#pragma unroll
  for (int g = 0; g < 2; ++g)
#pragma unroll
    for (int c = 0; c < 2; ++c) {
      asrc[g][c] = A  + (size_t)(m0 + c * 128 + g * 64 + (w << 3) + l3) * lda + kbeg + su;
      bsrc[g][c] = BT + (size_t)(n0 + (c * 2 + (w >> 2)) * 64 + g * 32 + ((w & 3) << 3) + l3) * ldb + kbeg + su;
    }

#define STAGE_A(buf, g, kk) do { \
    gload_lds16(asrc[g][0] + (kk), &As[buf][g][(w << 3)][0]);      \
    gload_lds16(asrc[g][1] + (kk), &As[buf][g][64 + (w << 3)][0]); \
  } while (0)
#define STAGE_B(buf, g, kk) do { \
    gload_lds16(bsrc[g][0] + (kk), &Bs[buf][g][(w << 3)][0]);      \
    gload_lds16(bsrc[g][1] + (kk), &Bs[buf][g][64 + (w << 3)][0]); \
  } while (0)

  // ---- fragment read addressing (swizzled)
  const int arow = (wr << 6) + n16;               // + fm*16, grp = mh
  const int brow = (wc << 5) + n16;               // + fn*16, grp = nh
  const int sw0 = ((qd ^ (n16 & 7)) << 3);        // ks=0
  const int sw1 = (((4 + qd) ^ (n16 & 7)) << 3);  // ks=1

#define READ_A(AA, mh, buf) do { \
  _Pragma("unroll") for (int fm = 0; fm < 4; ++fm) { \
    AA[fm][0] = *(const bf16x8*)&As[buf][mh][arow + fm * 16][sw0]; \
    AA[fm][1] = *(const bf16x8*)&As[buf][mh][arow + fm * 16][sw1]; \
  } } while (0)
#define READ_B(BB, g, buf) do { \
  _Pragma("unroll") for (int fn = 0; fn < 2; ++fn) { \
    BB[fn][0] = *(const bf16x8*)&Bs[buf][g][brow + fn * 16][sw0]; \
    BB[fn][1] = *(const bf16x8*)&Bs[buf][g][brow + fn * 16][sw1]; \
  } } while (0)

  f32x4 acc[8][4];
#pragma unroll
  for (int i = 0; i < 8; ++i)
#pragma unroll
    for (int j = 0; j < 4; ++j) acc[i][j] = (f32x4){0.f, 0.f, 0.f, 0.f};

#define MFMA_QUAD(mh, nh, AA, BB) do { \
  _Pragma("unroll") for (int fm = 0; fm < 4; ++fm) \
  _Pragma("unroll") for (int fn = 0; fn < 2; ++fn) { \
    acc[(mh) * 4 + fm][(nh) * 2 + fn] = mfma16(AA[fm][0], BB[fn][0], acc[(mh) * 4 + fm][(nh) * 2 + fn]); \
    acc[(mh) * 4 + fm][(nh) * 2 + fn] = mfma16(AA[fm][1], BB[fn][1], acc[(mh) * 4 + fm][(nh) * 2 + fn]); \
  } } while (0)

  // ---- prologue: K0 all 4 halves, then early halves of K1
  STAGE_A(0, 0, 0); STAGE_B(0, 0, 0);
  STAGE_A(0, 1, 0); STAGE_B(0, 1, 0);
  if (NT > 1) { STAGE_A(1, 0, 64); STAGE_B(1, 0, 64); }
  if (NT > 1) VMCNT(8); else VMCNT(4);   // retire K0.grp0 stages
  SBAR; BARRIER;

  bf16x8 a[4][2], b0[2][2], b1[2][2];
  for (int t = 0; t < NT; ++t) {
    const int p = t & 1, pn = p ^ 1;
    const int knx  = (t + 1) << 6;
    const int knx2 = (t + 2) << 6;
    const bool s1 = (t + 1 < NT), s2 = (t + 2 < NT);

    // ---- phase 1: quadrant (0,0)
    READ_A(a, 0, p); READ_B(b0, 0, p);
    if (s1) STAGE_A(pn, 1, knx);
    if (s1) { VMCNT(6); } else { VMCNT(0); }
    SBAR; BARRIER; LGKMCNT0; SBAR;
    __builtin_amdgcn_s_setprio(1); MFMA_QUAD(0, 0, a, b0); __builtin_amdgcn_s_setprio(0);
    SBAR; BARRIER;
    // ---- phase 2: quadrant (0,1)
    READ_B(b1, 1, p);
    if (s1) STAGE_B(pn, 1, knx);
    SBAR; BARRIER; LGKMCNT0; SBAR;
    __builtin_amdgcn_s_setprio(1); MFMA_QUAD(0, 1, a, b1); __builtin_amdgcn_s_setprio(0);
    SBAR; BARRIER;
    // ---- phase 3: quadrant (1,0)  (reuses b0 regs; reloads a from grp1)
    READ_A(a, 1, p);
    if (s2) STAGE_A(p, 0, knx2);
    SBAR; BARRIER; LGKMCNT0; SBAR;
    __builtin_amdgcn_s_setprio(1); MFMA_QUAD(1, 0, a, b0); __builtin_amdgcn_s_setprio(0);
    SBAR; BARRIER;
    // ---- phase 4: quadrant (1,1)  (no new reads)
    if (s2) STAGE_B(p, 0, knx2);
    if (s1) { if (s2) { VMCNT(8); } else { VMCNT(4); } }
    SBAR; BARRIER;
    __builtin_amdgcn_s_setprio(1); MFMA_QUAD(1, 1, a, b1); __builtin_amdgcn_s_setprio(0);
    SBAR; BARRIER;
  }

  // ---- epilogue. Frag map: col=n16, row=qd*4+r within each 16x16.
  if (MODE == 3) {
#pragma unroll
    for (int fm = 0; fm < 8; ++fm)
#pragma unroll
      for (int fn = 0; fn < 4; ++fn) {
        const int col  = n0 + (wc << 6) + (fn << 4) + n16;
        const int rowb = m0 + (wr << 7) + (fm << 4) + (qd << 2);
#pragma unroll
        for (int r = 0; r < 4; ++r) {
          if (use_atomic) atomicAdd(&Cf[(size_t)(rowb + r) * ldc_ + col], acc[fm][fn][r]);
          else            Cf[(size_t)(rowb + r) * ldc_ + col] = acc[fm][fn][r];
        }
      }
  } else {
#pragma unroll
    for (int fm = 0; fm < 8; ++fm)
#pragma unroll
      for (int fn = 0; fn < 4; ++fn) {
        const int col  = n0 + (wc << 6) + (fn << 4) + n16;
        const int rowb = m0 + (wr << 7) + (fm << 4) + (qd << 2);
        const float bc = (MODE == 4 && !rowbias) ? bias[col] : 0.f;
#pragma unroll
        for (int r = 0; r < 4; ++r) {
          float v = acc[fm][fn][r];
          if (MODE == 4) v += rowbias ? bias[rowb + r] : bc;
          if (MODE == 2) v *= 0.03125f;
          Cb[(size_t)(rowb + r) * ldc_ + col] = f2bf(v);
        }
      }
  }
#undef STAGE_A
#undef STAGE_B
#undef READ_A
#undef READ_B
#undef MFMA_QUAD
}

// ---------------------------------------------------------------------------
// softmax_rows: in-place row softmax on S -> P (bf16), causal+padding masked,
// normalized. Rows < n_padd -> zeros (fixed up later). Each row writes keys
// [0, ceil256(i+1)) so PV's 256-wide tile K-loop reads 0s above the diagonal.
// ---------------------------------------------------------------------------
__global__ __launch_bounds__(256) void softmax_rows(
    unsigned short* __restrict__ P, const int* __restrict__ np_p, int T) {
  __shared__ float red[8];
  const int i = blockIdx.x;
  const int np = *np_p;
  const int klen = ((i >> 8) + 1) << 8;     // 256-tile boundary for PV
  const int tid = threadIdx.x, lane = tid & 63, w = tid >> 6;
  const int j0 = tid << 4;
  unsigned short* rowp = P + (size_t)i * T;
  const bool act = j0 < klen;

  if (i < np) {
    if (act) {
      uint4 z = {0, 0, 0, 0};
      *(uint4*)(rowp + j0) = z;
      *(uint4*)(rowp + j0 + 8) = z;
    }
    return;
  }

  float v[16];
  float mx = -3.0e38f;
  if (act) {
    uint4 u0 = *(const uint4*)(rowp + j0);
    uint4 u1 = *(const uint4*)(rowp + j0 + 8);
    const unsigned int uu[8] = {u0.x, u0.y, u0.z, u0.w, u1.x, u1.y, u1.z, u1.w};
#pragma unroll
    for (int u = 0; u < 8; ++u) {
      v[2 * u]     = bf2f(uu[u] & 0xffff);
      v[2 * u + 1] = bf2f(uu[u] >> 16);
    }
#pragma unroll
    for (int u = 0; u < 16; ++u) {
      const int j = j0 + u;
      if (j > i || j < np) v[u] = -3.0e38f;
      mx = fmaxf(mx, v[u]);
    }
  }
  mx = fmaxf(mx, __shfl_xor(mx, 32));
  mx = fmaxf(mx, __shfl_xor(mx, 16));
  mx = fmaxf(mx, __shfl_xor(mx, 8));
  mx = fmaxf(mx, __shfl_xor(mx, 4));
  mx = fmaxf(mx, __shfl_xor(mx, 2));
  mx = fmaxf(mx, __shfl_xor(mx, 1));
  if (lane == 0) red[w] = mx;
  __syncthreads();
  const float M = fmaxf(fmaxf(red[0], red[1]), fmaxf(red[2], red[3]));

  float sum = 0.f;
  if (act) {
#pragma unroll
    for (int u = 0; u < 16; ++u) {
      const float p = (v[u] > -1.0e30f) ? __expf(v[u] - M) : 0.f;
      v[u] = p;
      sum += p;
    }
  }
  sum += __shfl_xor(sum, 32);
  sum += __shfl_xor(sum, 16);
  sum += __shfl_xor(sum, 8);
  sum += __shfl_xor(sum, 4);
  sum += __shfl_xor(sum, 2);
  sum += __shfl_xor(sum, 1);
  if (lane == 0) red[4 + w] = sum;
  __syncthreads();
  const float inv = 1.0f / (red[4] + red[5] + red[6] + red[7]);

  if (act) {
    unsigned int o[8];
#pragma unroll
    for (int u = 0; u < 8; ++u) {
      const unsigned int lo = f2bf(v[2 * u] * inv);
      const unsigned int hi = f2bf(v[2 * u + 1] * inv);
      o[u] = lo | (hi << 16);
    }
    uint4 s0 = {o[0], o[1], o[2], o[3]};
    uint4 s1 = {o[4], o[5], o[6], o[7]};
    *(uint4*)(rowp + j0) = s0;
    *(uint4*)(rowp + j0 + 8) = s1;
  }
}

// ---------------------------------------------------------------------------
// padfix: rows < n_padd get uniform attention over ALL T keys (mean of V)
// ---------------------------------------------------------------------------
__global__ __launch_bounds__(256) void padfix(
    const unsigned short* __restrict__ vtb, const int* __restrict__ np_p,
    float* __restrict__ out, int T) {
  const int np = *np_p;
  const int row0 = blockIdx.x * 32;
  if (row0 >= np) return;
  const int pc = min(np - row0, 32);
  const int c4 = threadIdx.x << 2;
  float a[4] = {0.f, 0.f, 0.f, 0.f};
#pragma unroll
  for (int c = 0; c < 4; ++c) {
    const unsigned short* vr = vtb + (size_t)(c4 + c) * T;
    for (int j = 0; j < T; j += 8) {
      uint4 v = *(const uint4*)(vr + j);
      a[c] += bf2f(v.x & 0xffff) + bf2f(v.x >> 16) + bf2f(v.y & 0xffff) + bf2f(v.y >> 16)
            + bf2f(v.z & 0xffff) + bf2f(v.z >> 16) + bf2f(v.w & 0xffff) + bf2f(v.w >> 16);
    }
  }
  const float inv = 1.0f / (float)T;
  float4 rv = {a[0] * inv, a[1] * inv, a[2] * inv, a[3] * inv};
  for (int r = 0; r < pc; ++r)
    *(float4*)(out + (size_t)(row0 + r) * C_DIM + c4) = rv;
}

// ---------------------------------------------------------------------------
extern "C" void kernel_launch(void* const* d_in, const int* in_sizes, int n_in,
                              void* d_out, int out_size, void* d_ws, size_t ws_size,
                              hipStream_t stream) {
  const float* x    = (const float*)d_in[0];
  const float* W    = (const float*)d_in[1];
  const float* b    = (const float*)d_in[2];
  const int* n_padd = (const int*)d_in[3];
  float* out = (float*)d_out;

  const int T = in_sizes[0] / C_DIM;
  // ws layout (overlapping lifetimes):
  //   [0,16M)  qkb [T][2048] bf16   (Q|K, persistent until PV)
  //   [16,24M) vtb [1024][T] bf16   (V^T, persistent)
  //   [24M..)  phase1: xb [T][1024] (8M) + WT [3072][1024] (6M)
  //            phase2: P  [T][T] bf16 (33.5M) overlays xb/WT
  unsigned short* qkb = (unsigned short*)d_ws;
  unsigned short* vtb = qkb + (size_t)T * QKS;
  unsigned short* xb  = vtb + (size_t)C_DIM * T;
  unsigned short* WT  = xb  + (size_t)T * C_DIM;
  unsigned short* P   = xb;

  // merged cast + transpose
  const int nc = (T * C_DIM) >> 10;
  prep<<<nc + 768, 256, 0, stream>>>(x, W, xb, WT, nc);

  // Merged QKV + zero-fill of out[512:] on the idle CUs (grid padded to 256)
  {
    const int nQK = (T >> 8) * (QKS >> 8);
    const int nV  = (C_DIM >> 8) * (T >> 8);
    int grid = nQK + nV + 64;
    gemm256<4><<<grid, 512, 0, stream>>>(
        xb, WT, qkb, b, C_DIM, C_DIM, QKS, T, out);
  }
  // S = Q @ K^T * 1/32  (lower-triangle 256-tiles), bf16 [T][T]
  gemm256<2><<<dim3(T >> 8, T >> 8), 512, 0, stream>>>(
      qkb, qkb + C_DIM, P, b, QKS, QKS, T, T, nullptr);
  // P = softmax(S) row-wise (normalized, masked, 256-col zero-fill)
  softmax_rows<<<T, 256, 0, stream>>>(P, n_padd, T);
  // O = P @ V: balanced split-K (max chunk 640 K), one round <= 256 blocks
  {
    const int nyt = T >> 8;
    int slots = 0;
    for (int bi = 0; bi < nyt; ++bi) {
      const int units = (bi + 1) << 2;
      slots += ((units + 9) / 10) << 2;
    }
    gemm256<3><<<slots, 512, 0, stream>>>(
        P, vtb, out, b, T, T, C_DIM, T, nullptr);
  }
  padfix<<<T / 32, 256, 0, stream>>>(vtb, n_padd, out, T);
}

// Round 13
// 222.218 us; speedup vs baseline: 1.0433x; 1.0433x over previous
//
#include <hip/hip_runtime.h>
#include <hip/hip_bf16.h>
#include <math.h>

#define C_DIM 1024
#define QKS  2048    // Q|K row stride in bf16 workspace

typedef __attribute__((ext_vector_type(8))) short bf16x8;   // 8 bf16 = 4 VGPRs
typedef __attribute__((ext_vector_type(4))) float f32x4;    // MFMA C/D

__device__ __forceinline__ unsigned short f2bf(float f) {
  __hip_bfloat16 h = __float2bfloat16(f);
  return *(reinterpret_cast<unsigned short*>(&h));
}
__device__ __forceinline__ float bf2f(unsigned short u) {
  return __uint_as_float(((unsigned int)u) << 16);
}
__device__ __forceinline__ f32x4 mfma16(bf16x8 a, bf16x8 b, f32x4 c) {
  return __builtin_amdgcn_mfma_f32_16x16x32_bf16(a, b, c, 0, 0, 0);
}
__device__ __forceinline__ void gload_lds16(const unsigned short* g,
                                            unsigned short* l) {
  __builtin_amdgcn_global_load_lds(
      (const __attribute__((address_space(1))) void*)(g),
      (__attribute__((address_space(3))) void*)(l), 16, 0, 0);
}

#define VMCNT(n)  asm volatile("s_waitcnt vmcnt(" #n ")" ::: "memory")
#define LGKMCNT0  asm volatile("s_waitcnt lgkmcnt(0)" ::: "memory")
#define SBAR      __builtin_amdgcn_sched_barrier(0)
#define BARRIER   __builtin_amdgcn_s_barrier()

// ---------------------------------------------------------------------------
// prep: merged {cast x fp32 -> xb bf16} + {W [1024][3072] fp32 -> WT
// [3072][1024] bf16 transpose}. Blocks [0,nc): cast; blocks [nc,nc+768):
// one 64x64 transpose tile each.
// ---------------------------------------------------------------------------
__global__ __launch_bounds__(256) void prep(
    const float* __restrict__ x, const float* __restrict__ W,
    unsigned short* __restrict__ xb, unsigned short* __restrict__ WT, int nc) {
  __shared__ float Ls[64][65];
  const int id = (int)blockIdx.x;
  if (id < nc) {
    const int i = (id * 256 + threadIdx.x) << 2;
    float4 v = *(const float4*)(x + i);
    ushort4 u;
    u.x = f2bf(v.x); u.y = f2bf(v.y); u.z = f2bf(v.z); u.w = f2bf(v.w);
    *(ushort4*)(xb + i) = u;
    return;
  }
  const int id2 = id - nc;
  const int n0 = (id2 % 48) * 64;
  const int k0 = (id2 / 48) * 64;
  const int c = (threadIdx.x & 15) << 2;
  const int r = threadIdx.x >> 4;
#pragma unroll
  for (int rr = 0; rr < 64; rr += 16) {
    float4 v = *(const float4*)(W + (size_t)(k0 + r + rr) * 3072 + n0 + c);
    Ls[r + rr][c + 0] = v.x; Ls[r + rr][c + 1] = v.y;
    Ls[r + rr][c + 2] = v.z; Ls[r + rr][c + 3] = v.w;
  }
  __syncthreads();
#pragma unroll
  for (int rr = 0; rr < 64; rr += 16) {
    const int X = r + rr;
    ushort4 u;
    u.x = f2bf(Ls[c + 0][X]); u.y = f2bf(Ls[c + 1][X]);
    u.z = f2bf(Ls[c + 2][X]); u.w = f2bf(Ls[c + 3][X]);
    *(ushort4*)(WT + (size_t)(n0 + X) * C_DIM + k0 + c) = u;
  }
}

// ---------------------------------------------------------------------------
// gemm256<MODE>: 256x256-tile, BK=64, 512-thread (8-wave, 2Mx4N) 8-phase
// GEMM with counted vmcnt (T3+T4), LDS XOR-swizzle (T2), setprio (T5).
// K-loop uses RAW s_barrier + counted vmcnt -- no __syncthreads (no vmcnt(0)
// drain). Per K-tile: 4 phases; phase = {ds_read quadrant | stage 1 half-tile
// (2 global_load_lds)} -> BARa -> lgkmcnt(0) -> prio1 -> 16 MFMA -> prio0 ->
// BARb. Waits one phase AHEAD of the reads they protect:
//   phase1: vmcnt(6)  protects phase-2/3 reads (B.C1, A.R1 of this K-tile)
//   phase4: vmcnt(8)  protects next iter's phase-1 reads (A.R0, B.C0)
// Stage slots (2 loads each): p1: A(t+1).grp1  p2: B(t+1).grp1
//                             p3: A(t+2).grp0  p4: B(t+2).grp0
// LDS layout: As[buf][grp][128][64]; A row -> grp=(row>>6)&1. B col ->
// grp=(col>>5)&1. Swizzle: 16B-unit u at row r holds k-unit u^(r&7); global
// source pre-permuted to match (rule #21 both-sides). Conflicts measured 0.
// MODE 4: merged QKV (QK: bf16+bias[col]; V^T: bf16+bias[row])
// MODE 2: S = Q K^T * 1/32, lower-triangle 256-tiles, bf16
// MODE 3: O = P V, causal split-K chunks of 1024, fp32 out (+atomics)
// ---------------------------------------------------------------------------
template <int MODE>
__global__ __launch_bounds__(512) void gemm256(
    const unsigned short* __restrict__ A_, const unsigned short* __restrict__ BT_,
    void* __restrict__ Cv, const float* __restrict__ bias_,
    int lda, int ldb, int ldc, int T) {
  __shared__ __align__(16) unsigned short As[2][2][128][64];  // 64 KB
  __shared__ __align__(16) unsigned short Bs[2][2][128][64];  // 64 KB

  const int tid = threadIdx.x, lane = tid & 63, w = tid >> 6;
  const int wr = w >> 2, wc = w & 3;          // wave grid 2M x 4N
  const int qd = lane >> 4, n16 = lane & 15;

  const unsigned short* A  = A_;
  const unsigned short* BT = BT_;
  const float* bias = bias_;
  unsigned short* Cb = (unsigned short*)Cv;
  float* Cf = (float*)Cv;
  int ldc_ = ldc;
  int m0, n0, kbeg = 0, kend = C_DIM;
  bool use_atomic = false, rowbias = false;

  if (MODE == 4) {
    const int nQKx = QKS >> 8;
    const int nQK  = (T >> 8) * nQKx;
    int id = (int)blockIdx.x;
    if (id < nQK) {                      // Q|K part: xb @ WT^T
      m0 = (id / nQKx) << 8; n0 = (id % nQKx) << 8;
    } else {                             // V^T part: Wv^T @ xb^T
      id -= nQK;
      const int nVx = T >> 8;
      m0 = (id / nVx) << 8; n0 = (id % nVx) << 8;
      A  = BT_ + (size_t)QKS * C_DIM;
      BT = A_;
      Cb = (unsigned short*)Cv + (size_t)T * QKS;   // vtb
      bias = bias_ + QKS; rowbias = true; ldc_ = T;
    }
  } else if (MODE == 2) {
    if ((int)blockIdx.x > (int)blockIdx.y) return;  // upper triangle: skip
    m0 = (int)blockIdx.y << 8; n0 = (int)blockIdx.x << 8;
  } else {  // MODE 3: causal PV, K chunks of 1024
    const int nnx = C_DIM >> 8;
    int id = (int)blockIdx.x;
    const int nx = id % nnx;
    int s = id / nnx;
    int bi = 0;
    while (s >= ((bi >> 2) + 1)) { s -= (bi >> 2) + 1; ++bi; }
    m0 = bi << 8; n0 = nx << 8;
    kbeg = s << 10;
    const int kfull = (bi + 1) << 8;
    kend = kbeg + 1024 < kfull ? kbeg + 1024 : kfull;
    use_atomic = (kfull > 1024);                    // rows >=1024 pre-zeroed
  }

  const int NT = (kend - kbeg) >> 6;    // K-tiles of 64 (>=1)

  // ---- staging source pointers (pre-swizzled global k-unit, rule #21)
  const int l3 = lane >> 3;                       // = (phys LDS row)&7
  const int su = (((lane & 7) ^ l3) << 3);        // swizzled k elem offset
  const unsigned short* asrc[2][2];
  const unsigned short* bsrc[2][2];
#pragma unroll
  for (int g = 0; g < 2; ++g)
#pragma unroll
    for (int c = 0; c < 2; ++c) {
      asrc[g][c] = A  + (size_t)(m0 + c * 128 + g * 64 + (w << 3) + l3) * lda + kbeg + su;
      bsrc[g][c] = BT + (size_t)(n0 + (c * 2 + (w >> 2)) * 64 + g * 32 + ((w & 3) << 3) + l3) * ldb + kbeg + su;
    }

#define STAGE_A(buf, g, kk) do { \
    gload_lds16(asrc[g][0] + (kk), &As[buf][g][(w << 3)][0]);      \
    gload_lds16(asrc[g][1] + (kk), &As[buf][g][64 + (w << 3)][0]); \
  } while (0)
#define STAGE_B(buf, g, kk) do { \
    gload_lds16(bsrc[g][0] + (kk), &Bs[buf][g][(w << 3)][0]);      \
    gload_lds16(bsrc[g][1] + (kk), &Bs[buf][g][64 + (w << 3)][0]); \
  } while (0)

  // ---- fragment read addressing (swizzled)
  const int arow = (wr << 6) + n16;               // + fm*16, grp = mh
  const int brow = (wc << 5) + n16;               // + fn*16, grp = nh
  const int sw0 = ((qd ^ (n16 & 7)) << 3);        // ks=0
  const int sw1 = (((4 + qd) ^ (n16 & 7)) << 3);  // ks=1

#define READ_A(AA, mh, buf) do { \
  _Pragma("unroll") for (int fm = 0; fm < 4; ++fm) { \
    AA[fm][0] = *(const bf16x8*)&As[buf][mh][arow + fm * 16][sw0]; \
    AA[fm][1] = *(const bf16x8*)&As[buf][mh][arow + fm * 16][sw1]; \
  } } while (0)
#define READ_B(BB, g, buf) do { \
  _Pragma("unroll") for (int fn = 0; fn < 2; ++fn) { \
    BB[fn][0] = *(const bf16x8*)&Bs[buf][g][brow + fn * 16][sw0]; \
    BB[fn][1] = *(const bf16x8*)&Bs[buf][g][brow + fn * 16][sw1]; \
  } } while (0)

  f32x4 acc[8][4];
#pragma unroll
  for (int i = 0; i < 8; ++i)
#pragma unroll
    for (int j = 0; j < 4; ++j) acc[i][j] = (f32x4){0.f, 0.f, 0.f, 0.f};

#define MFMA_QUAD(mh, nh, AA, BB) do { \
  _Pragma("unroll") for (int fm = 0; fm < 4; ++fm) \
  _Pragma("unroll") for (int fn = 0; fn < 2; ++fn) { \
    acc[(mh) * 4 + fm][(nh) * 2 + fn] = mfma16(AA[fm][0], BB[fn][0], acc[(mh) * 4 + fm][(nh) * 2 + fn]); \
    acc[(mh) * 4 + fm][(nh) * 2 + fn] = mfma16(AA[fm][1], BB[fn][1], acc[(mh) * 4 + fm][(nh) * 2 + fn]); \
  } } while (0)

  // ---- prologue: K0 all 4 halves, then early halves of K1
  STAGE_A(0, 0, 0); STAGE_B(0, 0, 0);
  STAGE_A(0, 1, 0); STAGE_B(0, 1, 0);
  if (NT > 1) { STAGE_A(1, 0, 64); STAGE_B(1, 0, 64); }
  if (NT > 1) VMCNT(8); else VMCNT(4);   // retire K0.grp0 stages
  SBAR; BARRIER;

  bf16x8 a[4][2], b0[2][2], b1[2][2];
  for (int t = 0; t < NT; ++t) {
    const int p = t & 1, pn = p ^ 1;
    const int knx  = (t + 1) << 6;
    const int knx2 = (t + 2) << 6;
    const bool s1 = (t + 1 < NT), s2 = (t + 2 < NT);

    // ---- phase 1: quadrant (0,0)
    READ_A(a, 0, p); READ_B(b0, 0, p);
    if (s1) STAGE_A(pn, 1, knx);
    if (s1) { VMCNT(6); } else { VMCNT(0); }
    SBAR; BARRIER; LGKMCNT0; SBAR;
    __builtin_amdgcn_s_setprio(1); MFMA_QUAD(0, 0, a, b0); __builtin_amdgcn_s_setprio(0);
    SBAR; BARRIER;
    // ---- phase 2: quadrant (0,1)
    READ_B(b1, 1, p);
    if (s1) STAGE_B(pn, 1, knx);
    SBAR; BARRIER; LGKMCNT0; SBAR;
    __builtin_amdgcn_s_setprio(1); MFMA_QUAD(0, 1, a, b1); __builtin_amdgcn_s_setprio(0);
    SBAR; BARRIER;
    // ---- phase 3: quadrant (1,0)  (reuses b0 regs; reloads a from grp1)
    READ_A(a, 1, p);
    if (s2) STAGE_A(p, 0, knx2);
    SBAR; BARRIER; LGKMCNT0; SBAR;
    __builtin_amdgcn_s_setprio(1); MFMA_QUAD(1, 0, a, b0); __builtin_amdgcn_s_setprio(0);
    SBAR; BARRIER;
    // ---- phase 4: quadrant (1,1)  (no new reads)
    if (s2) STAGE_B(p, 0, knx2);
    if (s1) { if (s2) { VMCNT(8); } else { VMCNT(4); } }
    SBAR; BARRIER;
    __builtin_amdgcn_s_setprio(1); MFMA_QUAD(1, 1, a, b1); __builtin_amdgcn_s_setprio(0);
    SBAR; BARRIER;
  }

  // ---- epilogue. Frag map: col=n16, row=qd*4+r within each 16x16.
  if (MODE == 3) {
#pragma unroll
    for (int fm = 0; fm < 8; ++fm)
#pragma unroll
      for (int fn = 0; fn < 4; ++fn) {
        const int col  = n0 + (wc << 6) + (fn << 4) + n16;
        const int rowb = m0 + (wr << 7) + (fm << 4) + (qd << 2);
#pragma unroll
        for (int r = 0; r < 4; ++r) {
          if (use_atomic) atomicAdd(&Cf[(size_t)(rowb + r) * ldc_ + col], acc[fm][fn][r]);
          else            Cf[(size_t)(rowb + r) * ldc_ + col] = acc[fm][fn][r];
        }
      }
  } else {
#pragma unroll
    for (int fm = 0; fm < 8; ++fm)
#pragma unroll
      for (int fn = 0; fn < 4; ++fn) {
        const int col  = n0 + (wc << 6) + (fn << 4) + n16;
        const int rowb = m0 + (wr << 7) + (fm << 4) + (qd << 2);
        const float bc = (MODE == 4 && !rowbias) ? bias[col] : 0.f;
#pragma unroll
        for (int r = 0; r < 4; ++r) {
          float v = acc[fm][fn][r];
          if (MODE == 4) v += rowbias ? bias[rowb + r] : bc;
          if (MODE == 2) v *= 0.03125f;
          Cb[(size_t)(rowb + r) * ldc_ + col] = f2bf(v);
        }
      }
  }
#undef STAGE_A
#undef STAGE_B
#undef READ_A
#undef READ_B
#undef MFMA_QUAD
}

// ---------------------------------------------------------------------------
// softmax_rows: in-place row softmax on S -> P (bf16), causal+padding masked,
// normalized. Rows < n_padd -> zeros (fixed up later). Each row writes keys
// [0, ceil256(i+1)) so PV's 256-wide tile K-loop reads 0s above the diagonal.
// Also grid-strides a zero-fill of out rows [1024, T) (PV atomic targets) --
// folded zero_hi; completes before PV launches (same stream).
// ---------------------------------------------------------------------------
__global__ __launch_bounds__(256) void softmax_rows(
    unsigned short* __restrict__ P, const int* __restrict__ np_p, int T,
    float* __restrict__ out) {
  __shared__ float red[8];
  // folded zero_hi: out rows [1024, T)
  {
    const int nz4 = ((T - 1024) * C_DIM) >> 2;
    const int gidx = (int)blockIdx.x * 256 + threadIdx.x;
    const int stride = (int)gridDim.x * 256;
    const float4 z4 = {0.f, 0.f, 0.f, 0.f};
    for (int i = gidx; i < nz4; i += stride)
      *(float4*)(out + (size_t)1024 * C_DIM + ((size_t)i << 2)) = z4;
  }
  const int i = blockIdx.x;
  const int np = *np_p;
  const int klen = ((i >> 8) + 1) << 8;     // 256-tile boundary for PV
  const int tid = threadIdx.x, lane = tid & 63, w = tid >> 6;
  const int j0 = tid << 4;
  unsigned short* rowp = P + (size_t)i * T;
  const bool act = j0 < klen;

  if (i < np) {
    if (act) {
      uint4 z = {0, 0, 0, 0};
      *(uint4*)(rowp + j0) = z;
      *(uint4*)(rowp + j0 + 8) = z;
    }
    return;
  }

  float v[16];
  float mx = -3.0e38f;
  if (act) {
    uint4 u0 = *(const uint4*)(rowp + j0);
    uint4 u1 = *(const uint4*)(rowp + j0 + 8);
    const unsigned int uu[8] = {u0.x, u0.y, u0.z, u0.w, u1.x, u1.y, u1.z, u1.w};
#pragma unroll
    for (int u = 0; u < 8; ++u) {
      v[2 * u]     = bf2f(uu[u] & 0xffff);
      v[2 * u + 1] = bf2f(uu[u] >> 16);
    }
#pragma unroll
    for (int u = 0; u < 16; ++u) {
      const int j = j0 + u;
      if (j > i || j < np) v[u] = -3.0e38f;
      mx = fmaxf(mx, v[u]);
    }
  }
  mx = fmaxf(mx, __shfl_xor(mx, 32));
  mx = fmaxf(mx, __shfl_xor(mx, 16));
  mx = fmaxf(mx, __shfl_xor(mx, 8));
  mx = fmaxf(mx, __shfl_xor(mx, 4));
  mx = fmaxf(mx, __shfl_xor(mx, 2));
  mx = fmaxf(mx, __shfl_xor(mx, 1));
  if (lane == 0) red[w] = mx;
  __syncthreads();
  const float M = fmaxf(fmaxf(red[0], red[1]), fmaxf(red[2], red[3]));

  float sum = 0.f;
  if (act) {
#pragma unroll
    for (int u = 0; u < 16; ++u) {
      const float p = (v[u] > -1.0e30f) ? __expf(v[u] - M) : 0.f;
      v[u] = p;
      sum += p;
    }
  }
  sum += __shfl_xor(sum, 32);
  sum += __shfl_xor(sum, 16);
  sum += __shfl_xor(sum, 8);
  sum += __shfl_xor(sum, 4);
  sum += __shfl_xor(sum, 2);
  sum += __shfl_xor(sum, 1);
  if (lane == 0) red[4 + w] = sum;
  __syncthreads();
  const float inv = 1.0f / (red[4] + red[5] + red[6] + red[7]);

  if (act) {
    unsigned int o[8];
#pragma unroll
    for (int u = 0; u < 8; ++u) {
      const unsigned int lo = f2bf(v[2 * u] * inv);
      const unsigned int hi = f2bf(v[2 * u + 1] * inv);
      o[u] = lo | (hi << 16);
    }
    uint4 s0 = {o[0], o[1], o[2], o[3]};
    uint4 s1 = {o[4], o[5], o[6], o[7]};
    *(uint4*)(rowp + j0) = s0;
    *(uint4*)(rowp + j0 + 8) = s1;
  }
}

// ---------------------------------------------------------------------------
// padfix: rows < n_padd get uniform attention over ALL T keys (mean of V)
// ---------------------------------------------------------------------------
__global__ __launch_bounds__(256) void padfix(
    const unsigned short* __restrict__ vtb, const int* __restrict__ np_p,
    float* __restrict__ out, int T) {
  const int np = *np_p;
  const int row0 = blockIdx.x * 32;
  if (row0 >= np) return;
  const int pc = min(np - row0, 32);
  const int c4 = threadIdx.x << 2;
  float a[4] = {0.f, 0.f, 0.f, 0.f};
#pragma unroll
  for (int c = 0; c < 4; ++c) {
    const unsigned short* vr = vtb + (size_t)(c4 + c) * T;
    for (int j = 0; j < T; j += 8) {
      uint4 v = *(const uint4*)(vr + j);
      a[c] += bf2f(v.x & 0xffff) + bf2f(v.x >> 16) + bf2f(v.y & 0xffff) + bf2f(v.y >> 16)
            + bf2f(v.z & 0xffff) + bf2f(v.z >> 16) + bf2f(v.w & 0xffff) + bf2f(v.w >> 16);
    }
  }
  const float inv = 1.0f / (float)T;
  float4 rv = {a[0] * inv, a[1] * inv, a[2] * inv, a[3] * inv};
  for (int r = 0; r < pc; ++r)
    *(float4*)(out + (size_t)(row0 + r) * C_DIM + c4) = rv;
}

// ---------------------------------------------------------------------------
extern "C" void kernel_launch(void* const* d_in, const int* in_sizes, int n_in,
                              void* d_out, int out_size, void* d_ws, size_t ws_size,
                              hipStream_t stream) {
  const float* x    = (const float*)d_in[0];
  const float* W    = (const float*)d_in[1];
  const float* b    = (const float*)d_in[2];
  const int* n_padd = (const int*)d_in[3];
  float* out = (float*)d_out;

  const int T = in_sizes[0] / C_DIM;
  // ws layout (overlapping lifetimes):
  //   [0,16M)  qkb [T][2048] bf16   (Q|K, persistent until PV)
  //   [16,24M) vtb [1024][T] bf16   (V^T, persistent)
  //   [24M..)  phase1: xb [T][1024] (8M) + WT [3072][1024] (6M)
  //            phase2: P  [T][T] bf16 (33.5M) overlays xb/WT
  unsigned short* qkb = (unsigned short*)d_ws;
  unsigned short* vtb = qkb + (size_t)T * QKS;
  unsigned short* xb  = vtb + (size_t)C_DIM * T;
  unsigned short* WT  = xb  + (size_t)T * C_DIM;
  unsigned short* P   = xb;

  // merged cast + transpose
  const int nc = (T * C_DIM) >> 10;
  prep<<<nc + 768, 256, 0, stream>>>(x, W, xb, WT, nc);

  // Merged QKV: blocks [0,nQK) -> Q|K, rest -> V^T (vtb = Cv + T*QKS)
  {
    const int nQK = (T >> 8) * (QKS >> 8);
    const int nV  = (C_DIM >> 8) * (T >> 8);
    gemm256<4><<<nQK + nV, 512, 0, stream>>>(
        xb, WT, qkb, b, C_DIM, C_DIM, QKS, T);
  }
  // S = Q @ K^T * 1/32  (lower-triangle 256-tiles), bf16 [T][T]
  gemm256<2><<<dim3(T >> 8, T >> 8), 512, 0, stream>>>(
      qkb, qkb + C_DIM, P, b, QKS, QKS, T, T);
  // P = softmax(S) (normalized, masked, 256-col zero-fill) + zero out[1024:]
  softmax_rows<<<T, 256, 0, stream>>>(P, n_padd, T, out);
  // O = P @ V (causal split-K chunks of 1024)
  {
    const int nyt = T >> 8;
    int slots = 0;
    for (int bi = 0; bi < nyt; ++bi) slots += (bi >> 2) + 1;
    gemm256<3><<<slots * (C_DIM >> 8), 512, 0, stream>>>(
        P, vtb, out, b, T, T, C_DIM, T);
  }
  padfix<<<T / 32, 256, 0, stream>>>(vtb, n_padd, out, T);
}